// Round 3
// baseline (105.341 us; speedup 1.0000x reference)
//
#include <hip/hip_runtime.h>

#define D 256
#define MAXB 128
#define BATCH 4

typedef float f32x4 __attribute__((ext_vector_type(4)));

// Single fused kernel:
//  - every block computes the 4 offset scans (128 lengths, L2-hit loads, cheap)
//  - block 0 writes the out_len tail (as float values)
//  - grid-stride loop, BATCH=4 rows per wave-iteration: 4 independent binary
//    searches, then 4 nontemporal loads in flight, then 4 stores (4x MLP).
__global__ __launch_bounds__(256) void hstu_preproc_fused(
    const float* __restrict__ item, const float* __restrict__ action,
    const float* __restrict__ c0v, const float* __restrict__ c1v,
    const int* __restrict__ item_len, const int* __restrict__ c0_len,
    const int* __restrict__ c1_len,
    float* __restrict__ out, int total_rows, int Bn) {
    __shared__ int s_oo[MAXB + 1];
    __shared__ int s_io[MAXB + 1];
    __shared__ int s_c0[MAXB + 1];
    __shared__ int s_c1[MAXB + 1];

    int t = threadIdx.x;
    int li = 0, l0 = 0, l1 = 0;
    if (t < Bn) {
        li = item_len[t];
        l0 = c0_len[t];
        l1 = c1_len[t];
    }
    if (t == 0) { s_oo[0] = 0; s_io[0] = 0; s_c0[0] = 0; s_c1[0] = 0; }
    if (t < Bn) {
        s_oo[t + 1] = 2 * li + l0 + l1;
        s_io[t + 1] = li;
        s_c0[t + 1] = l0;
        s_c1[t + 1] = l1;
    }
    __syncthreads();
    // Hillis-Steele inclusive scan over positions 1..Bn -> exclusive offsets [0..Bn]
    for (int off = 1; off < Bn; off <<= 1) {
        int a = 0, b = 0, c = 0, d = 0;
        int idx = t + 1;
        bool act = (t < Bn) && (idx > off);
        if (act) {
            a = s_oo[idx - off];
            b = s_io[idx - off];
            c = s_c0[idx - off];
            d = s_c1[idx - off];
        }
        __syncthreads();
        if (act) {
            s_oo[idx] += a;
            s_io[idx] += b;
            s_c0[idx] += c;
            s_c1[idx] += d;
        }
        __syncthreads();
    }

    // out_len tail (second reference output), float-encoded, block 0 only
    if (blockIdx.x == 0 && t < Bn) {
        out[(size_t)total_rows * D + t] = (float)(s_oo[t + 1] - s_oo[t]);
    }

    int wave = t >> 6;
    int lane = t & 63;
    int gwave = blockIdx.x * 4 + wave;
    int nwaves = gridDim.x * 4;

    for (int r0 = gwave; r0 < total_rows; r0 += nwaves * BATCH) {
        const float* src0 = nullptr;
        const float* src1 = nullptr;
        const float* src2 = nullptr;
        const float* src3 = nullptr;
        const float* srcs[BATCH] = {nullptr, nullptr, nullptr, nullptr};
        f32x4 v0, v1, v2, v3;

        // Phase 1: compute all sources (independent binary searches overlap)
        #pragma unroll
        for (int k = 0; k < BATCH; k++) {
            int r = r0 + k * nwaves;
            if (r >= total_rows) break;
            int lo = 0, hi = Bn;
            while (hi - lo > 1) {
                int mid = (lo + hi) >> 1;
                if (r >= s_oo[mid]) lo = mid; else hi = mid;
            }
            int s = lo;
            int pos = r - s_oo[s];
            int l0c = s_c0[s + 1] - s_c0[s];
            int l1c = s_c1[s + 1] - s_c1[s];
            const float* src;
            if (pos < l0c) {
                src = c0v + (size_t)(s_c0[s] + pos) * D;
            } else if (pos < l0c + l1c) {
                src = c1v + (size_t)(s_c1[s] + pos - l0c) * D;
            } else {
                int q = pos - l0c - l1c;
                int tk = s_io[s] + (q >> 1);
                src = ((q & 1) ? action : item) + (size_t)tk * D;
            }
            if (k == 0) src0 = src;
            else if (k == 1) src1 = src;
            else if (k == 2) src2 = src;
            else src3 = src;
        }

        // Phase 2: issue all loads (up to 4 in flight before any wait)
        if (src0) v0 = __builtin_nontemporal_load(reinterpret_cast<const f32x4*>(src0) + lane);
        if (src1) v1 = __builtin_nontemporal_load(reinterpret_cast<const f32x4*>(src1) + lane);
        if (src2) v2 = __builtin_nontemporal_load(reinterpret_cast<const f32x4*>(src2) + lane);
        if (src3) v3 = __builtin_nontemporal_load(reinterpret_cast<const f32x4*>(src3) + lane);

        // Phase 3: stores
        if (src0) __builtin_nontemporal_store(v0, reinterpret_cast<f32x4*>(out + (size_t)(r0 + 0 * nwaves) * D) + lane);
        if (src1) __builtin_nontemporal_store(v1, reinterpret_cast<f32x4*>(out + (size_t)(r0 + 1 * nwaves) * D) + lane);
        if (src2) __builtin_nontemporal_store(v2, reinterpret_cast<f32x4*>(out + (size_t)(r0 + 2 * nwaves) * D) + lane);
        if (src3) __builtin_nontemporal_store(v3, reinterpret_cast<f32x4*>(out + (size_t)(r0 + 3 * nwaves) * D) + lane);
        (void)srcs;
    }
}

extern "C" void kernel_launch(void* const* d_in, const int* in_sizes, int n_in,
                              void* d_out, int out_size, void* d_ws, size_t ws_size,
                              hipStream_t stream) {
    const float* item   = (const float*)d_in[0];
    const float* action = (const float*)d_in[1];
    const float* c0v    = (const float*)d_in[2];
    const float* c1v    = (const float*)d_in[3];
    const int* item_len = (const int*)d_in[4];
    const int* c0_len   = (const int*)d_in[5];
    const int* c1_len   = (const int*)d_in[6];
    float* out = (float*)d_out;

    int Bn = in_sizes[4];                      // 128
    int total_rows = (out_size - Bn) / D;      // 262400

    // 2048 blocks x 256 threads = 8192 waves, fully resident (8 blocks/CU),
    // 32 rows per wave (8 batch-iterations of 4).
    int grid = 2048;
    hstu_preproc_fused<<<grid, 256, 0, stream>>>(
        item, action, c0v, c1v, item_len, c0_len, c1_len, out, total_rows, Bn);
}

// Round 4
// 98.177 us; speedup vs baseline: 1.0730x; 1.0730x over previous
//
#include <hip/hip_runtime.h>

#define D 256
#define MAXB 128

typedef float f32x4 __attribute__((ext_vector_type(4)));

// Single fused kernel (v2 structure + 2-deep software pipeline):
//  - every block computes the 4 offset scans (128 lengths, L2-hit loads, cheap)
//  - block 0 writes the out_len tail (as float values)
//  - grid-stride loop: one 64-lane wave copies one 1KB output row per iteration;
//    the NEXT row's binsearch + load are issued before the current row's store,
//    so stores never wait on a just-issued load and binsearch latency overlaps
//    the in-flight load. Nontemporal (streaming) hints on row data.
__global__ __launch_bounds__(256) void hstu_preproc_fused(
    const float* __restrict__ item, const float* __restrict__ action,
    const float* __restrict__ c0v, const float* __restrict__ c1v,
    const int* __restrict__ item_len, const int* __restrict__ c0_len,
    const int* __restrict__ c1_len,
    float* __restrict__ out, int total_rows, int Bn) {
    __shared__ int s_oo[MAXB + 1];
    __shared__ int s_io[MAXB + 1];
    __shared__ int s_c0[MAXB + 1];
    __shared__ int s_c1[MAXB + 1];

    int t = threadIdx.x;
    int li = 0, l0 = 0, l1 = 0;
    if (t < Bn) {
        li = item_len[t];
        l0 = c0_len[t];
        l1 = c1_len[t];
    }
    if (t == 0) { s_oo[0] = 0; s_io[0] = 0; s_c0[0] = 0; s_c1[0] = 0; }
    if (t < Bn) {
        s_oo[t + 1] = 2 * li + l0 + l1;
        s_io[t + 1] = li;
        s_c0[t + 1] = l0;
        s_c1[t + 1] = l1;
    }
    __syncthreads();
    // Hillis-Steele inclusive scan over positions 1..Bn -> exclusive offsets [0..Bn]
    for (int off = 1; off < Bn; off <<= 1) {
        int a = 0, b = 0, c = 0, d = 0;
        int idx = t + 1;
        bool act = (t < Bn) && (idx > off);
        if (act) {
            a = s_oo[idx - off];
            b = s_io[idx - off];
            c = s_c0[idx - off];
            d = s_c1[idx - off];
        }
        __syncthreads();
        if (act) {
            s_oo[idx] += a;
            s_io[idx] += b;
            s_c0[idx] += c;
            s_c1[idx] += d;
        }
        __syncthreads();
    }

    // out_len tail (second reference output), float-encoded, block 0 only
    if (blockIdx.x == 0 && t < Bn) {
        out[(size_t)total_rows * D + t] = (float)(s_oo[t + 1] - s_oo[t]);
    }

    int wave = t >> 6;
    int lane = t & 63;
    int gwave = blockIdx.x * 4 + wave;
    int nwaves = gridDim.x * 4;

    // row -> source-row pointer (wave-uniform binary search over LDS offsets)
    auto find_src = [&](int r) -> const float* {
        int lo = 0, hi = Bn;
        while (hi - lo > 1) {
            int mid = (lo + hi) >> 1;
            if (r >= s_oo[mid]) lo = mid; else hi = mid;
        }
        int s = lo;
        int pos = r - s_oo[s];
        int l0c = s_c0[s + 1] - s_c0[s];
        int l1c = s_c1[s + 1] - s_c1[s];
        if (pos < l0c)       return c0v + (size_t)(s_c0[s] + pos) * D;
        if (pos < l0c + l1c) return c1v + (size_t)(s_c1[s] + pos - l0c) * D;
        int q = pos - l0c - l1c;            // position within interleaved sequence
        int tk = s_io[s] + (q >> 1);        // source token row
        return ((q & 1) ? action : item) + (size_t)tk * D;
    };

    int r = gwave;
    if (r >= total_rows) return;

    // prologue: load row r
    const float* src = find_src(r);
    f32x4 vcur = __builtin_nontemporal_load(
        reinterpret_cast<const f32x4*>(src) + lane);

    for (;;) {
        int rn = r + nwaves;
        bool have_next = rn < total_rows;
        f32x4 vnext;
        if (have_next) {
            const float* srcn = find_src(rn);   // overlaps vcur's in-flight load
            vnext = __builtin_nontemporal_load(
                reinterpret_cast<const f32x4*>(srcn) + lane);
        }
        // vcur's load was issued an iteration ago -> store waits ~0 here
        __builtin_nontemporal_store(
            vcur, reinterpret_cast<f32x4*>(out + (size_t)r * D) + lane);
        if (!have_next) break;
        vcur = vnext;
        r = rn;
    }
}

extern "C" void kernel_launch(void* const* d_in, const int* in_sizes, int n_in,
                              void* d_out, int out_size, void* d_ws, size_t ws_size,
                              hipStream_t stream) {
    const float* item   = (const float*)d_in[0];
    const float* action = (const float*)d_in[1];
    const float* c0v    = (const float*)d_in[2];
    const float* c1v    = (const float*)d_in[3];
    const int* item_len = (const int*)d_in[4];
    const int* c0_len   = (const int*)d_in[5];
    const int* c1_len   = (const int*)d_in[6];
    float* out = (float*)d_out;

    int Bn = in_sizes[4];                      // 128
    int total_rows = (out_size - Bn) / D;      // 262400

    // 2048 blocks x 256 threads = 8192 waves, fully resident (8 blocks/CU),
    // ~32 rows per wave via grid-stride.
    int grid = 2048;
    hstu_preproc_fused<<<grid, 256, 0, stream>>>(
        item, action, c0v, c1v, item_len, c0_len, c1_len, out, total_rows, Bn);
}